// Round 1
// baseline (21871.201 us; speedup 1.0000x reference)
//
#include <hip/hip_runtime.h>

#define N_NODES 50000
#define L_SCALES 4
#define E_NNZ 1600000
#define C 128

// Y[row, c] = sum_k feat[row, l, k] * W[k, c]
// Block: 256 threads, handles 16 rows; thread t -> local row t/16, 8 channels (t%16)*8.
// W staged in LDS in 4 k-tiles of 32 (16 KB), X rows staged once (8 KB).
__global__ __launch_bounds__(256) void gemm_kernel(
    const float* __restrict__ feat,   // [N, L, C]
    const float* __restrict__ W,      // [C, C]
    float* __restrict__ Y,            // [N, C]
    int l)
{
    __shared__ float Ws[32 * C];      // 16 KB k-tile of W
    __shared__ float Xs[16 * C];      // 8 KB: 16 feature rows

    int t = threadIdx.x;
    int row0 = blockIdx.x * 16;

    for (int i = t; i < 16 * C; i += 256) {
        int r = row0 + (i >> 7);
        Xs[i] = (r < N_NODES) ? feat[((size_t)r * L_SCALES + l) * C + (i & 127)] : 0.f;
    }

    int rr = t >> 4;            // local row 0..15
    int c0 = (t & 15) * 8;      // channel group
    float acc[8] = {0.f, 0.f, 0.f, 0.f, 0.f, 0.f, 0.f, 0.f};

    for (int kt = 0; kt < 4; ++kt) {
        __syncthreads();        // Xs ready (first iter) / prev compute done
        for (int i = t; i < 32 * C; i += 256)
            Ws[i] = W[kt * 32 * C + i];
        __syncthreads();
        #pragma unroll
        for (int k = 0; k < 32; ++k) {
            float x = Xs[rr * C + kt * 32 + k];
            #pragma unroll
            for (int j = 0; j < 8; ++j)
                acc[j] += x * Ws[k * C + c0 + j];
        }
    }

    int row = row0 + rr;
    if (row < N_NODES) {
        #pragma unroll
        for (int j = 0; j < 8; ++j)
            Y[(size_t)row * C + c0 + j] = acc[j];
    }
}

// Scatter-add spmm: Zout[row * out_stride + c] += v(*theta[col]) * X[col * C + c]
// One thread per (edge, 4-channel group): 32 threads/edge, float4 gather.
__global__ __launch_bounds__(256) void spmm_kernel(
    const int*   __restrict__ rows,
    const int*   __restrict__ cols,
    const float* __restrict__ vals,
    const float* __restrict__ X,       // [N, C]
    float*       __restrict__ Zout,    // base (maybe offset), row stride out_stride
    const float* __restrict__ theta,   // nullptr for first spmm
    int out_stride,
    int nEdges)
{
    long long idx = (long long)blockIdx.x * blockDim.x + threadIdx.x;
    int e  = (int)(idx >> 5);
    int c4 = (int)(idx & 31);
    if (e >= nEdges) return;

    int row = rows[e];
    int col = cols[e];
    float v = vals[e];
    if (theta) v *= theta[col];

    float4 x = ((const float4*)(X + (size_t)col * C))[c4];
    float* z = Zout + (size_t)row * out_stride + c4 * 4;
    atomicAdd(z + 0, v * x.x);
    atomicAdd(z + 1, v * x.y);
    atomicAdd(z + 2, v * x.z);
    atomicAdd(z + 3, v * x.w);
}

extern "C" void kernel_launch(void* const* d_in, const int* in_sizes, int n_in,
                              void* d_out, int out_size, void* d_ws, size_t ws_size,
                              hipStream_t stream) {
    const int*   phi_idx  = (const int*)  d_in[0];   // [L, 2, E]
    const float* phi_val  = (const float*)d_in[1];   // [L, E]
    const int*   pinv_idx = (const int*)  d_in[2];   // [L, 2, E]
    const float* pinv_val = (const float*)d_in[3];   // [L, E]
    const float* feat     = (const float*)d_in[4];   // [N, L, C]
    const float* W        = (const float*)d_in[5];   // [C, C]
    const float* theta    = (const float*)d_in[6];   // [N]
    float* out = (float*)d_out;

    float* Y = (float*)d_ws;                         // [N, C]  25.6 MB
    float* Z = Y + (size_t)N_NODES * C;              // [N, C]  25.6 MB

    // d_out is poisoned before every launch; atomics need zeros.
    hipMemsetAsync(out, 0, (size_t)out_size * sizeof(float), stream);

    dim3 gemmGrid((N_NODES + 15) / 16);
    long long spmmThreads = (long long)E_NNZ * 32;
    int spmmBlocks = (int)((spmmThreads + 255) / 256);

    for (int l = 0; l < L_SCALES; ++l) {
        // Y = feat[:, l, :] @ W
        gemm_kernel<<<gemmGrid, 256, 0, stream>>>(feat, W, Y, l);

        // Z = phi_inv_l @ Y
        hipMemsetAsync(Z, 0, (size_t)N_NODES * C * sizeof(float), stream);
        spmm_kernel<<<spmmBlocks, 256, 0, stream>>>(
            pinv_idx + (size_t)l * 2 * E_NNZ,            // rows
            pinv_idx + (size_t)l * 2 * E_NNZ + E_NNZ,    // cols
            pinv_val + (size_t)l * E_NNZ,
            Y, Z, nullptr, C, E_NNZ);

        // out[:, l, :] = phi_l @ (theta ⊙ Z)
        spmm_kernel<<<spmmBlocks, 256, 0, stream>>>(
            phi_idx + (size_t)l * 2 * E_NNZ,
            phi_idx + (size_t)l * 2 * E_NNZ + E_NNZ,
            phi_val + (size_t)l * E_NNZ,
            Z, out + l * C, theta, L_SCALES * C, E_NNZ);
    }
}

// Round 2
// 2236.726 us; speedup vs baseline: 9.7782x; 9.7782x over previous
//
#include <hip/hip_runtime.h>

#define N_NODES 50000
#define L_SCALES 4
#define E_NNZ 1600000
#define C 128
#define ELL_W 64
#define OVF_CAP 8192

// ---------------- GEMM: Y[row,c] = sum_k feat[row,l,k] * W[k,c] ----------------
__global__ __launch_bounds__(256) void gemm_kernel(
    const float* __restrict__ feat,   // [N, L, C]
    const float* __restrict__ W,      // [C, C]
    float* __restrict__ Y,            // [N, C]
    int l)
{
    __shared__ float Ws[32 * C];      // 16 KB k-tile of W
    __shared__ float Xs[16 * C];      // 8 KB: 16 feature rows

    int t = threadIdx.x;
    int row0 = blockIdx.x * 16;

    for (int i = t; i < 16 * C; i += 256) {
        int r = row0 + (i >> 7);
        Xs[i] = (r < N_NODES) ? feat[((size_t)r * L_SCALES + l) * C + (i & 127)] : 0.f;
    }

    int rr = t >> 4;            // local row 0..15
    int c0 = (t & 15) * 8;      // channel group
    float acc[8] = {0.f, 0.f, 0.f, 0.f, 0.f, 0.f, 0.f, 0.f};

    for (int kt = 0; kt < 4; ++kt) {
        __syncthreads();
        for (int i = t; i < 32 * C; i += 256)
            Ws[i] = W[kt * 32 * C + i];
        __syncthreads();
        #pragma unroll
        for (int k = 0; k < 32; ++k) {
            float x = Xs[rr * C + kt * 32 + k];
            #pragma unroll
            for (int j = 0; j < 8; ++j)
                acc[j] += x * Ws[k * C + c0 + j];
        }
    }

    int row = row0 + rr;
    if (row < N_NODES) {
        #pragma unroll
        for (int j = 0; j < 8; ++j)
            Y[(size_t)row * C + c0 + j] = acc[j];
    }
}

// ---------------- ELL build: bucket edges by row ----------------
__global__ __launch_bounds__(256) void build_ell(
    const int*   __restrict__ rows,
    const int*   __restrict__ cols,
    const float* __restrict__ vals,
    int*   __restrict__ cnt,        // [N], pre-zeroed
    int*   __restrict__ ell_col,    // [N*ELL_W]
    float* __restrict__ ell_val,    // [N*ELL_W]
    int*   __restrict__ ovf_n,      // [1], pre-zeroed
    int*   __restrict__ ovf_row,
    int*   __restrict__ ovf_col,
    float* __restrict__ ovf_val)
{
    int e = blockIdx.x * blockDim.x + threadIdx.x;
    if (e >= E_NNZ) return;
    int r = rows[e];
    int c = cols[e];
    float v = vals[e];
    int pos = atomicAdd(&cnt[r], 1);
    if (pos < ELL_W) {
        ell_col[(size_t)r * ELL_W + pos] = c;
        ell_val[(size_t)r * ELL_W + pos] = v;
    } else {
        int k = atomicAdd(ovf_n, 1);
        if (k < OVF_CAP) {
            ovf_row[k] = r;
            ovf_col[k] = c;
            ovf_val[k] = v;
        }
    }
}

// ---------------- SpMM (gather): out[row] = (row_scale?) * sum_e val_e * X[col_e] ----------------
// One wave per row; lane j preloads edge j (coalesced); shfl-broadcast; float2/lane.
__global__ __launch_bounds__(256) void spmm_ell(
    const int*   __restrict__ ell_col,
    const float* __restrict__ ell_val,
    const int*   __restrict__ cnt,
    const int*   __restrict__ ovf_n,
    const int*   __restrict__ ovf_row,
    const int*   __restrict__ ovf_col,
    const float* __restrict__ ovf_val,
    const float* __restrict__ X,          // [N, C]
    const float* __restrict__ row_scale,  // nullptr or theta[N]
    float*       __restrict__ out,        // base (maybe offset)
    int out_stride)
{
    int row  = (blockIdx.x * 256 + threadIdx.x) >> 6;
    int lane = threadIdx.x & 63;
    if (row >= N_NODES) return;

    int n   = cnt[row];
    int ncl = n < ELL_W ? n : ELL_W;

    int   mycol = ell_col[(size_t)row * ELL_W + lane];
    float myval = ell_val[(size_t)row * ELL_W + lane];

    float2 acc = {0.f, 0.f};
    for (int j = 0; j < ncl; ++j) {
        int   c = __shfl(mycol, j);
        float v = __shfl(myval, j);
        float2 x = ((const float2*)(X + (size_t)c * C))[lane];
        acc.x += v * x.x;
        acc.y += v * x.y;
    }

    if (n > ELL_W) {   // astronomically rare; correctness fallback
        int m = *ovf_n;
        if (m > OVF_CAP) m = OVF_CAP;
        for (int k = 0; k < m; ++k) {
            if (ovf_row[k] == row) {
                int   c = ovf_col[k];
                float v = ovf_val[k];
                float2 x = ((const float2*)(X + (size_t)c * C))[lane];
                acc.x += v * x.x;
                acc.y += v * x.y;
            }
        }
    }

    if (row_scale) {
        float s = row_scale[row];
        acc.x *= s;
        acc.y *= s;
    }
    ((float2*)(out + (size_t)row * out_stride))[lane] = acc;
}

extern "C" void kernel_launch(void* const* d_in, const int* in_sizes, int n_in,
                              void* d_out, int out_size, void* d_ws, size_t ws_size,
                              hipStream_t stream) {
    const int*   phi_idx  = (const int*)  d_in[0];   // [L, 2, E]
    const float* phi_val  = (const float*)d_in[1];   // [L, E]
    const int*   pinv_idx = (const int*)  d_in[2];   // [L, 2, E]
    const float* pinv_val = (const float*)d_in[3];   // [L, E]
    const float* feat     = (const float*)d_in[4];   // [N, L, C]
    const float* W        = (const float*)d_in[5];   // [C, C]
    const float* theta    = (const float*)d_in[6];   // [N]
    float* out = (float*)d_out;

    // Workspace layout (≈77.3 MB)
    float* Y       = (float*)d_ws;                      // N*C
    float* Z       = Y + (size_t)N_NODES * C;           // N*C
    int*   ell_col = (int*)(Z + (size_t)N_NODES * C);   // N*ELL_W
    float* ell_val = (float*)(ell_col + (size_t)N_NODES * ELL_W); // N*ELL_W
    int*   cnt     = (int*)(ell_val + (size_t)N_NODES * ELL_W);   // N
    int*   ovf_n   = cnt + N_NODES;                     // 1 (adjacent to cnt for single memset)
    int*   ovf_row = ovf_n + 1;
    int*   ovf_col = ovf_row + OVF_CAP;
    float* ovf_val = (float*)(ovf_col + OVF_CAP);

    dim3 gemmGrid((N_NODES + 15) / 16);
    dim3 buildGrid((E_NNZ + 255) / 256);
    dim3 spmmGrid((N_NODES * 64 + 255) / 256);   // one wave per row

    for (int l = 0; l < L_SCALES; ++l) {
        // Y = feat[:, l, :] @ W
        gemm_kernel<<<gemmGrid, 256, 0, stream>>>(feat, W, Y, l);

        // ---- Z = theta ⊙ (phi_inv_l @ Y) ----
        hipMemsetAsync(cnt, 0, (N_NODES + 1) * sizeof(int), stream);  // cnt + ovf_n
        build_ell<<<buildGrid, 256, 0, stream>>>(
            pinv_idx + (size_t)l * 2 * E_NNZ,
            pinv_idx + (size_t)l * 2 * E_NNZ + E_NNZ,
            pinv_val + (size_t)l * E_NNZ,
            cnt, ell_col, ell_val, ovf_n, ovf_row, ovf_col, ovf_val);
        spmm_ell<<<spmmGrid, 256, 0, stream>>>(
            ell_col, ell_val, cnt, ovf_n, ovf_row, ovf_col, ovf_val,
            Y, theta, Z, C);

        // ---- out[:, l, :] = phi_l @ Z ----
        hipMemsetAsync(cnt, 0, (N_NODES + 1) * sizeof(int), stream);
        build_ell<<<buildGrid, 256, 0, stream>>>(
            phi_idx + (size_t)l * 2 * E_NNZ,
            phi_idx + (size_t)l * 2 * E_NNZ + E_NNZ,
            phi_val + (size_t)l * E_NNZ,
            cnt, ell_col, ell_val, ovf_n, ovf_row, ovf_col, ovf_val);
        spmm_ell<<<spmmGrid, 256, 0, stream>>>(
            ell_col, ell_val, cnt, ovf_n, ovf_row, ovf_col, ovf_val,
            Z, nullptr, out + l * C, L_SCALES * C);
    }
}